// Round 15
// baseline (214.928 us; speedup 1.0000x reference)
//
#include <hip/hip_runtime.h>
#include <hip/hip_bf16.h>

typedef unsigned short u16;
typedef __attribute__((ext_vector_type(8))) __bf16 bf16x8;
typedef __attribute__((ext_vector_type(4))) float f32x4;
typedef __attribute__((ext_vector_type(16))) float f32x16;

#define SEQ 2048
#define NB 2
#define NH 16
#define HD 64
#define DM 1024
#define LDQKV 3072
#define KF 576   // folded feature K: 512 h1 + 63 feats + 1 (constant term)
#define LOG2E 1.4426950408889634f
#define NSPL 2   // attention KV splits (16 tiles each)

__device__ __forceinline__ u16 f2bf(float f) {
    unsigned u = __float_as_uint(f);
    unsigned r = u + 0x7FFFu + ((u >> 16) & 1u);
    return (u16)(r >> 16);
}
__device__ __forceinline__ float bf2f(u16 x) {
    return __uint_as_float(((unsigned)x) << 16);
}
__device__ __forceinline__ unsigned cvt_pk_bf16(float a, float b) {
    unsigned r;
    asm("v_cvt_pk_bf16_f32 %0, %1, %2" : "=v"(r) : "v"(a), "v"(b));
    return r;
}
// async global->LDS DMA, 16B per lane; lds dst wave-uniform base + lane*16B
__device__ __forceinline__ void gl_lds16(const u16* g, u16* l) {
    __builtin_amdgcn_global_load_lds((const __attribute__((address_space(1))) unsigned int*)g,
                                     (__attribute__((address_space(3))) unsigned int*)l, 16, 0, 0);
}
// a % b for a,b < 2^24, b >= 1, via exact fp32 division (trunc off-by-1 fixup)
__device__ __forceinline__ unsigned fmod_u24(unsigned a, unsigned b) {
    float q = truncf(__fdividef((float)a, (float)b));
    int r = (int)a - (int)((unsigned)q * b);
    r += (r < 0) ? (int)b : 0;
    r -= (r >= (int)b) ? (int)b : 0;
    return (unsigned)r;
}

// -------- merged weight prep: z=0..3 transpose q(,scale)/k/v/o ; z=4 cast emb2_w -------
__global__ __launch_bounds__(256) void transw5_kernel(const float* __restrict__ q_w,
                                                      const float* __restrict__ k_w,
                                                      const float* __restrict__ v_w,
                                                      const float* __restrict__ o_w,
                                                      const float* __restrict__ emb2_w,
                                                      u16* __restrict__ WqkvT,
                                                      u16* __restrict__ WoT,
                                                      u16* __restrict__ Wc) {
    const int z = blockIdx.z;
    int tx = threadIdx.x, ty = threadIdx.y;
    if (z >= 4) {
        // cast emb2_w (512x1024 fp32 = 524288 floats) -> Wc rows 0..511 bf16, same layout
        int blin = blockIdx.y * 32 + blockIdx.x;     // 0..1023
        if (blin >= 512) return;                     // 512 blocks x 256 thr x 4 floats
        int i = (blin * 256 + ty * 32 + tx) * 4;
        float4 v = *(const float4*)&emb2_w[i];
        uint2 o;
        o.x = cvt_pk_bf16(v.x, v.y);
        o.y = cvt_pk_bf16(v.z, v.w);
        *(uint2*)&Wc[i] = o;
        return;
    }
    __shared__ float tl[32][33];
    const float* src = (z == 0) ? q_w : (z == 1) ? k_w : (z == 2) ? v_w : o_w;
    u16* dst = (z < 3) ? WqkvT + (size_t)z * 1024 * DM : WoT;
    const float scale = (z == 0) ? 0.125f * LOG2E : 1.0f;
    int n = blockIdx.x * 32 + tx;
    int kbase = blockIdx.y * 32;
#pragma unroll
    for (int i = 0; i < 4; ++i)
        tl[ty + i * 8][tx] = src[(size_t)(kbase + ty + i * 8) * DM + n];
    __syncthreads();
    int k = kbase + tx;
#pragma unroll
    for (int i = 0; i < 4; ++i) {
        int n2 = blockIdx.x * 32 + ty + i * 8;
        dst[(size_t)n2 * DM + k] = f2bf(tl[tx][ty + i * 8] * scale);
    }
}

// ---------------- fold feature weights into Wc rows 512..574; r=63 computes cvec ------
__global__ __launch_bounds__(256) void fold_kernel(const float* __restrict__ log_w,
                                                   const float* __restrict__ prime_w,
                                                   const float* __restrict__ div_w,
                                                   const float* __restrict__ bit_w,
                                                   const float* __restrict__ fus_w,
                                                   const float* __restrict__ emb2_b,
                                                   const float* __restrict__ fus_b,
                                                   const float* __restrict__ log_b,
                                                   const float* __restrict__ prime_b,
                                                   const float* __restrict__ div_b,
                                                   const float* __restrict__ bit_b,
                                                   u16* __restrict__ Wc) {
    const int r = blockIdx.y;  // 0..63
    const int n = blockIdx.x * 256 + threadIdx.x;
    if (r == 63) {
        // constant term: cvec = emb2_b + fus_b + biases pushed through fus_w
        float acc = emb2_b[n] + fus_b[n];
#pragma unroll 4
        for (int m = 0; m < 256; ++m) {
            acc += log_b[m]   * fus_w[(size_t)m * DM + n];
            acc += prime_b[m] * fus_w[(size_t)(256 + m) * DM + n];
            acc += div_b[m]   * fus_w[(size_t)(512 + m) * DM + n];
            acc += bit_b[m]   * fus_w[(size_t)(768 + m) * DM + n];
        }
        Wc[(size_t)575 * DM + n] = f2bf(acc);
        return;
    }
    const float* wrow; int chunk;
    if (r == 0)       { wrow = log_w;                 chunk = 0;   }
    else if (r < 11)  { wrow = prime_w + (r - 1) * 256; chunk = 256; }
    else if (r < 31)  { wrow = div_w + (r - 11) * 256;  chunk = 512; }
    else              { wrow = bit_w + (r - 31) * 256;  chunk = 768; }
    float acc = 0.f;
#pragma unroll 8
    for (int m = 0; m < 256; ++m)
        acc += wrow[m] * fus_w[(size_t)(chunk + m) * DM + n];
    Wc[(size_t)(512 + r) * DM + n] = f2bf(acc);
}

// -------- merged prep: blocks [0,8192)=bias2, [8192,12288)=feat, [12288,12300)=qkvb ----
// bias2 layout (R11): float idx = (((b*32+jt)*16 + rr)*2048 + i)*4 + e, rr = 8c+2g+hi
//   value = gcd-bias(i, j=jt*64+rr*4+e) * gcdw * log2e
__global__ __launch_bounds__(256) void prep_kernel(const int* __restrict__ enc,
                                                   const float* __restrict__ gcd_w,
                                                   const float* __restrict__ emb1_w,
                                                   const float* __restrict__ emb1_b,
                                                   const float* __restrict__ q_b,
                                                   const float* __restrict__ k_b,
                                                   const float* __restrict__ v_b,
                                                   float* __restrict__ bias2,
                                                   u16* __restrict__ F,
                                                   float* __restrict__ qkvb) {
    const int bx = blockIdx.x, t = threadIdx.x;
    if (bx < 8192) {
        int vi = bx * 256 + t;
        int i  = vi & 2047;
        int rr = (vi >> 11) & 15;
        int jt = (vi >> 15) & 31;
        int b  = vi >> 20;
        int j0 = jt * 64 + rr * 4;
        unsigned ei = (unsigned)enc[b * SEQ + i];
        float scale = gcd_w[0] * LOG2E;
        int4 ej4 = *(const int4*)&enc[b * SEQ + j0];
        f32x4 o;
#pragma unroll
        for (int e = 0; e < 4; ++e) {
            unsigned ej = (unsigned)((e == 0) ? ej4.x : (e == 1) ? ej4.y : (e == 2) ? ej4.z : ej4.w);
            unsigned r1 = fmod_u24(ei, ej + 1u);
            unsigned r2 = fmod_u24(ej, ei + 1u);
            float gg = (float)min(r1, r2);
            float mx = (float)(max(ei, ej) + 1u);
            o[e] = (i == j0 + e) ? 0.f : __fdividef(gg, mx) * scale;
        }
        *(f32x4*)&bias2[(size_t)vi * 4] = o;
    } else if (bx < 12288) {
        const int tok = bx - 8192;
        int e = enc[tok];
        float ef = (float)e;
        float nrm = ef / 2147483647.0f;
        for (int k = t; k < 512; k += 256)
            F[(size_t)tok * KF + k] = f2bf(fmaxf(nrm * emb1_w[k] + emb1_b[k], 0.f));
        if (t < 64) {
            float v;
            if (t == 0) v = logf(ef + 1.f);
            else if (t < 11) {
                const int pr[10] = {2, 3, 5, 7, 11, 13, 17, 19, 23, 29};
                v = (e % pr[t - 1] == 0) ? 1.f : 0.f;
            } else if (t < 31) {
                int tv = t - 11 + 2;
                v = (float)(e % tv) / (float)tv;
            } else if (t < 63) {
                int sh = t - 31;
                v = (float)((e >> sh) & 1);
            } else v = 1.0f;   // constant-term column: picks up cvec row of Wc
            F[(size_t)tok * KF + 512 + t] = f2bf(v);
        }
    } else {
        int i = (bx - 12288) * 256 + t;  // 0..3071
        const float C1 = 0.125f * LOG2E;
        qkvb[i] = (i < 1024) ? q_b[i] * C1 : (i < 2048 ? k_b[i - 1024] : v_b[i - 2048]);
    }
}

// ---------------- GEMM (m97 structure): C[M x N] = A @ BT^T (+ bias) ----------------
template <int OUT_BF16, int TN, int HB>
__global__ __launch_bounds__(256) void gemm_kernel(const u16* __restrict__ A,
                                                   const u16* __restrict__ BT,
                                                   const float* __restrict__ bias,
                                                   void* __restrict__ Cv,
                                                   int M, int N, int K) {
    constexpr int FN = TN / 32;
    __shared__ u16 As[128 * 32];
    __shared__ u16 Bs[TN * 32];
    const int t = threadIdx.x;
    const int w = t >> 6, l = t & 63, lr = l & 15, lg = l >> 4;
    const int m0 = blockIdx.y * 128, n0 = blockIdx.x * TN;
    const int wm = (w >> 1) * 64, wn = (w & 1) * (TN / 2);
    const int srow = l >> 2, scol = (l & 3) * 8;

    const u16* gA = &A[(size_t)(m0 + w * 32 + srow) * K + scol];
    u16* lA = &As[w * 1024];
    const u16* gB;
    u16* lB;
    if (TN == 128) { gB = &BT[(size_t)(n0 + w * 32 + srow) * K + scol]; lB = &Bs[w * 1024]; }
    else           { gB = &BT[(size_t)(n0 + w * 16 + srow) * K + scol]; lB = &Bs[w * 512];  }

    f32x4 acc[4][FN] = {};
    for (int k0 = 0; k0 < K; k0 += 32) {
        __syncthreads();
        gl_lds16(gA + k0, lA);
        gl_lds16(gA + k0 + (size_t)16 * K, lA + 512);
        if (TN == 128) {
            gl_lds16(gB + k0, lB);
            gl_lds16(gB + k0 + (size_t)16 * K, lB + 512);
        } else {
            gl_lds16(gB + k0, lB);
        }
        __syncthreads();
        bf16x8 a[4], b[FN];
#pragma unroll
        for (int i = 0; i < 4; ++i) a[i] = *(const bf16x8*)&As[(wm + i * 16 + lr) * 32 + lg * 8];
#pragma unroll
        for (int j = 0; j < FN; ++j) b[j] = *(const bf16x8*)&Bs[(wn + j * 16 + lr) * 32 + lg * 8];
#pragma unroll
        for (int mi = 0; mi < 4; ++mi)
#pragma unroll
            for (int ni = 0; ni < FN; ++ni)
                acc[mi][ni] = __builtin_amdgcn_mfma_f32_16x16x32_bf16(a[mi], b[ni], acc[mi][ni], 0, 0, 0);
    }
#pragma unroll
    for (int mi = 0; mi < 4; ++mi)
#pragma unroll
        for (int ni = 0; ni < FN; ++ni)
#pragma unroll
            for (int r = 0; r < 4; ++r) {
                int row = m0 + wm + mi * 16 + lg * 4 + r;
                int col = n0 + wn + ni * 16 + lr;
                float v = acc[mi][ni][r] + (HB ? bias[col] : 0.f);
                if (OUT_BF16)
                    ((u16*)Cv)[(size_t)row * N + col] = f2bf(v);
                else
                    ((float*)Cv)[(size_t)row * N + col] = v;
            }
}

// ---------------- V transpose: vT[b][h][d][s] = v[b][s][h][d] ----------------
__global__ __launch_bounds__(256) void vtrans_kernel(const u16* __restrict__ qkv,
                                                     u16* __restrict__ vT) {
    __shared__ u16 tile[64][72];
    int t = threadIdx.x;
    int s0 = blockIdx.x * 64, h = blockIdx.y, b = blockIdx.z;
    int sr = t >> 2, sc = (t & 3) * 16;
    const int4* g = (const int4*)&qkv[(size_t)(b * SEQ + s0 + sr) * LDQKV + 2048 + h * HD + sc];
    int4 v0 = g[0], v1 = g[1];
    *(int4*)&tile[sr][sc] = v0;
    *(int4*)&tile[sr][sc + 8] = v1;
    __syncthreads();
    int dl = sr, j0 = sc;
    u16 tmp[16];
#pragma unroll
    for (int jj = 0; jj < 16; ++jj) tmp[jj] = tile[j0 + jj][dl];
    u16* out = &vT[(size_t)((b * NH + h) * HD + dl) * SEQ + s0 + j0];
    *(int4*)&out[0] = *(int4*)&tmp[0];
    *(int4*)&out[8] = *(int4*)&tmp[8];
}

// ---------------- fused attention: 32x32x16 MFMA, 32KB LDS (P aliased into idle buf) --
// Per wave: 32 q rows. S^T = mfma32(K, Q) with bias C-init (loaded per-tile, no prefetch).
// KV-split x2 (16 tiles each) -> grid 1024 = one full 4-blocks/CU phase.
// C layout (m74/m101): col=lane&31, row=(reg&3)+8*(reg>>2)+4*(lane>>5).
#define KVB 64
#define SWZ(row, cb) ((((int)(row)) << 7) + (((int)(cb)) ^ ((((int)(row)) & 7) << 4)))

__global__ __launch_bounds__(256, 4) void attn_kernel(const u16* __restrict__ qkv,
                                                      const u16* __restrict__ vT,
                                                      const float* __restrict__ bias2,
                                                      u16* __restrict__ Opart,
                                                      float* __restrict__ Lp,
                                                      float* __restrict__ Mp) {
    __shared__ char smem[32768];   // [2][Kt 8KB | Vt 8KB]; P aliases the idle half
    const int t = threadIdx.x, w = t >> 6, l = t & 63;
    const int q5 = l & 31, hi = l >> 5;
    const int qt = blockIdx.x, h = blockIdx.y;
    const int b = blockIdx.z >> 1, sp = blockIdx.z & 1;
    const int qrow = qt * 128 + w * 32 + q5;
    const int jt0 = sp * 16;
    const int NT  = 16;
    const int j0s = jt0 * KVB;

    // Q B-frags: col=q=q5, k=d=16ks+8hi+j  (Q pre-scaled by 0.125*log2e)
    bf16x8 qf[4];
#pragma unroll
    for (int ks = 0; ks < 4; ++ks)
        qf[ks] = *(const bf16x8*)&qkv[(size_t)(b * SEQ + qrow) * LDQKV + h * HD + ks * 16 + hi * 8];

    // staging addresses
    const int sr = t >> 2, sc = (t & 3) * 16;
    const u16* gK = &qkv[(size_t)(b * SEQ + j0s + sr) * LDQKV + 1024 + h * HD + sc];
    const u16* gV = &vT[(size_t)((b * NH + h) * HD + sr) * SEQ + j0s + sc];
    // bias base: float idx = (((b*32+jt)*16 + rr)*2048 + i)*4 ; rr = 8c+2g+hi
    const float* gBl = &bias2[((((size_t)b * 32 + jt0) * 16 + hi) * 2048 + qrow) * 4];

    // prologue: prefetch tile 0 K/V
    int4 kr0 = *(const int4*)&gK[0], kr1 = *(const int4*)&gK[8];
    int4 vr0 = *(const int4*)&gV[0], vr1 = *(const int4*)&gV[8];

    float m_s = -1e30f, l_s = 0.f;
    f32x16 acc2[2] = {};

    for (int lt = 0; lt < NT; ++lt) {
        char* KtB = smem + (lt & 1) * 16384;
        char* VtB = KtB + 8192;
        char* PlB = smem + (((lt + 1) & 1) << 14) + (w << 12);   // idle buffer half
        // staged regs -> LDS (swizzled)
        *(int4*)(KtB + SWZ(sr, (t & 3) * 32))      = kr0;
        *(int4*)(KtB + SWZ(sr, (t & 3) * 32 + 16)) = kr1;
        *(int4*)(VtB + SWZ(sr, (t & 3) * 32))      = vr0;
        *(int4*)(VtB + SWZ(sr, (t & 3) * 32 + 16)) = vr1;
        if (lt < NT - 1) {
            kr0 = *(const int4*)&gK[(size_t)(lt + 1) * KVB * LDQKV];
            kr1 = *(const int4*)&gK[(size_t)(lt + 1) * KVB * LDQKV + 8];
            vr0 = *(const int4*)&gV[(lt + 1) * KVB];
            vr1 = *(const int4*)&gV[(lt + 1) * KVB + 8];
        }
        __syncthreads();

        // bias loads land directly in s2 sub-ranges (no prefetch regs, no copy)
        f32x16 s2[2];
        const float* tB = gBl + ((size_t)lt << 17);
#pragma unroll
        for (int c = 0; c < 2; ++c)
#pragma unroll
            for (int g = 0; g < 4; ++g)
                *(f32x4*)((float*)&s2[c] + 4 * g) =
                    *(const f32x4*)&tB[(size_t)(8 * c + 2 * g) << 13];

        // S^T = K @ Q^T : 8 mfma32
        __builtin_amdgcn_s_setprio(1);
#pragma unroll
        for (int ks = 0; ks < 4; ++ks)
#pragma unroll
            for (int c = 0; c < 2; ++c) {
                bf16x8 kf = *(const bf16x8*)(KtB + SWZ(32 * c + q5, ks * 32 + hi * 16));
                s2[c] = __builtin_amdgcn_mfma_f32_32x32x16_bf16(kf, qf[ks], s2[c], 0, 0, 0);
            }
        __builtin_amdgcn_s_setprio(0);

        // softmax (log2 domain): lane holds 32 of 64 kv for q=q5; partner l^32 the rest
        float tm = s2[0][0];
#pragma unroll
        for (int c = 0; c < 2; ++c)
#pragma unroll
            for (int r = 0; r < 16; ++r) tm = fmaxf(tm, s2[c][r]);
        tm = fmaxf(tm, __shfl_xor(tm, 32));

        if (__any(tm > m_s + 8.f)) {
            float mn = fmaxf(m_s, tm);
            float al = __builtin_exp2f(m_s - mn);
            l_s *= al;
            m_s = mn;
#pragma unroll
            for (int dc = 0; dc < 2; ++dc)
#pragma unroll
                for (int r = 0; r < 16; ++r) acc2[dc][r] *= al;
        }

        float ps = 0.f;
#pragma unroll
        for (int c = 0; c < 2; ++c)
#pragma unroll
            for (int r = 0; r < 16; ++r) {
                float p = __builtin_exp2f(s2[c][r] - m_s);
                s2[c][r] = p;
                ps += p;
            }
        ps += __shfl_xor(ps, 32);
        l_s += ps;

        // P -> per-wave LDS (in idle buffer): Pl[q][kv], b64 writes at kv = 32c+8g+4hi
#pragma unroll
        for (int c = 0; c < 2; ++c)
#pragma unroll
            for (int g = 0; g < 4; ++g) {
                uint2 u;
                u.x = cvt_pk_bf16(s2[c][4 * g + 0], s2[c][4 * g + 1]);
                u.y = cvt_pk_bf16(s2[c][4 * g + 2], s2[c][4 * g + 3]);
                *(uint2*)(PlB + SWZ(q5, (32 * c + 8 * g + 4 * hi) * 2)) = u;
            }
        asm volatile("s_waitcnt lgkmcnt(0)" ::: "memory");
        __builtin_amdgcn_sched_barrier(0);

        // PV: O^T = V^T @ P^T : 8 mfma32
        __builtin_amdgcn_s_setprio(1);
#pragma unroll
        for (int ks = 0; ks < 4; ++ks) {
            bf16x8 pb = *(const bf16x8*)(PlB + SWZ(q5, ks * 32 + hi * 16));
#pragma unroll
            for (int dc = 0; dc < 2; ++dc) {
                bf16x8 vf = *(const bf16x8*)(VtB + SWZ(32 * dc + q5, ks * 32 + hi * 16));
                acc2[dc] = __builtin_amdgcn_mfma_f32_32x32x16_bf16(vf, pb, acc2[dc], 0, 0, 0);
            }
        }
        __builtin_amdgcn_s_setprio(0);
        __syncthreads();   // P consumed before next iteration's staging overwrites it
    }

    // epilogue: unnormalized O~ + (m,l); lane reg r of acc2[dc] -> d = 32dc+8*(r>>2)+4hi+(r&3)
    u16* orow = &Opart[(size_t)((sp * NB + b) * SEQ + qrow) * DM + h * HD];
#pragma unroll
    for (int dc = 0; dc < 2; ++dc)
#pragma unroll
        for (int g = 0; g < 4; ++g) {
            uint2 u;
            u.x = cvt_pk_bf16(acc2[dc][4 * g + 0], acc2[dc][4 * g + 1]);
            u.y = cvt_pk_bf16(acc2[dc][4 * g + 2], acc2[dc][4 * g + 3]);
            *(uint2*)&orow[32 * dc + 8 * g + 4 * hi] = u;
        }
    if (hi == 0) {
        size_t idx = ((size_t)(sp * NB + b) * SEQ + qrow) * NH + h;
        Lp[idx] = l_s;
        Mp[idx] = m_s;
    }
}

// ---------------- combine the two KV-split partials ----------------
__global__ __launch_bounds__(256) void comb_kernel(const u16* __restrict__ Opart,
                                                   const float* __restrict__ Lp,
                                                   const float* __restrict__ Mp,
                                                   u16* __restrict__ attn_o) {
    int tid = blockIdx.x * 256 + threadIdx.x;
    int base = tid * 4;
    int b = base / (SEQ * DM);
    int rem = base - b * SEQ * DM;
    int i = rem / DM;
    int c = rem - i * DM;
    int h = c >> 6;
    size_t ix1 = ((size_t)b * SEQ + i) * NH + h;
    size_t ix2 = ((size_t)(NB + b) * SEQ + i) * NH + h;
    float m1 = Mp[ix1], m2 = Mp[ix2];
    float l1 = Lp[ix1], l2 = Lp[ix2];
    float ms = fmaxf(m1, m2);
    float a1 = __builtin_exp2f(m1 - ms), a2 = __builtin_exp2f(m2 - ms);
    float inv = 1.f / (a1 * l1 + a2 * l2);
    a1 *= inv; a2 *= inv;
    uint2 o1 = *(const uint2*)&Opart[((size_t)b * SEQ + i) * DM + c];
    uint2 o2 = *(const uint2*)&Opart[((size_t)(NB + b) * SEQ + i) * DM + c];
    float v0 = a1 * bf2f(o1.x & 0xFFFF) + a2 * bf2f(o2.x & 0xFFFF);
    float v1 = a1 * bf2f(o1.x >> 16)    + a2 * bf2f(o2.x >> 16);
    float v2 = a1 * bf2f(o1.y & 0xFFFF) + a2 * bf2f(o2.y & 0xFFFF);
    float v3 = a1 * bf2f(o1.y >> 16)    + a2 * bf2f(o2.y >> 16);
    uint2 u;
    u.x = cvt_pk_bf16(v0, v1);
    u.y = cvt_pk_bf16(v2, v3);
    *(uint2*)&attn_o[(size_t)(b * SEQ + i) * DM + c] = u;
}

extern "C" void kernel_launch(void* const* d_in, const int* in_sizes, int n_in,
                              void* d_out, int out_size, void* d_ws, size_t ws_size,
                              hipStream_t stream) {
    const float* q_w    = (const float*)d_in[0];
    const float* q_b    = (const float*)d_in[1];
    const float* k_w    = (const float*)d_in[2];
    const float* k_b    = (const float*)d_in[3];
    const float* v_w    = (const float*)d_in[4];
    const float* v_b    = (const float*)d_in[5];
    const float* o_w    = (const float*)d_in[6];
    const float* o_b    = (const float*)d_in[7];
    const float* emb1_w = (const float*)d_in[8];
    const float* emb1_b = (const float*)d_in[9];
    const float* emb2_w = (const float*)d_in[10];
    const float* emb2_b = (const float*)d_in[11];
    const float* log_w  = (const float*)d_in[12];
    const float* log_b  = (const float*)d_in[13];
    const float* prime_w= (const float*)d_in[14];
    const float* prime_b= (const float*)d_in[15];
    const float* div_w  = (const float*)d_in[16];
    const float* div_b  = (const float*)d_in[17];
    const float* bit_w  = (const float*)d_in[18];
    const float* bit_b  = (const float*)d_in[19];
    const float* fus_w  = (const float*)d_in[20];
    const float* fus_b  = (const float*)d_in[21];
    const float* gcd_weight = (const float*)d_in[23];
    const int*   enc    = (const int*)d_in[24];

    char* ws = (char*)d_ws;
    size_t off = 0;
    auto alloc = [&](size_t bytes) {
        char* p = ws + off;
        off += (bytes + 255) & ~size_t(255);
        return p;
    };
    u16*   WqkvT  = (u16*)alloc((size_t)3072 * DM * 2);
    u16*   WoT    = (u16*)alloc((size_t)DM * DM * 2);
    u16*   Wc     = (u16*)alloc((size_t)KF * DM * 2);
    u16*   W2T    = (u16*)alloc((size_t)3072 * KF * 2);
    float* qkvb   = (float*)alloc(3072 * 4);
    u16*   F      = (u16*)alloc((size_t)NB * SEQ * KF * 2);
    u16*   qkv    = (u16*)alloc((size_t)NB * SEQ * LDQKV * 2);
    u16*   vT     = (u16*)alloc((size_t)NB * NH * HD * SEQ * 2);
    float* bias2  = (float*)alloc((size_t)NB * SEQ * SEQ * 4);
    u16*   attn_o = (u16*)alloc((size_t)NB * SEQ * DM * 2);
    u16*   Opart  = (u16*)alloc((size_t)NSPL * NB * SEQ * DM * 2);
    float* Lp     = (float*)alloc((size_t)NSPL * NB * SEQ * NH * 4);
    float* Mp     = (float*)alloc((size_t)NSPL * NB * SEQ * NH * 4);
    (void)ws_size; (void)n_in; (void)in_sizes; (void)out_size;

    // weight prep (q_w pre-scaled so scores come out in log2 domain) + emb2 cast
    transw5_kernel<<<dim3(32, 32, 5), dim3(32, 8), 0, stream>>>(q_w, k_w, v_w, o_w, emb2_w,
                                                                WqkvT, WoT, Wc);
    fold_kernel<<<dim3(4, 64), 256, 0, stream>>>(log_w, prime_w, div_w, bit_w, fus_w,
                                                 emb2_b, fus_b, log_b, prime_b, div_b, bit_b, Wc);
    // bias2 + features + qkv bias in one launch
    prep_kernel<<<12300, 256, 0, stream>>>(enc, gcd_weight, emb1_w, emb1_b, q_b, k_b, v_b,
                                           bias2, F, qkvb);
    // W2T = WqkvT @ Wc^T   (3072 x 576, K=1024) -- hidden GEMM + cvec folded into weights
    gemm_kernel<1, 64, 0><<<dim3(KF / 64, 3072 / 128), 256, 0, stream>>>(WqkvT, Wc, nullptr, W2T,
                                                                         3072, KF, DM);
    // qkv = F @ W2T^T + qkvb   (K=576)
    gemm_kernel<1, 128, 1><<<dim3(3072 / 128, NB * SEQ / 128), 256, 0, stream>>>(F, W2T, qkvb, qkv,
                                                                                 NB * SEQ, 3072, KF);
    vtrans_kernel<<<dim3(SEQ / 64, NH, NB), 256, 0, stream>>>(qkv, vT);
    attn_kernel<<<dim3(SEQ / 128, NH, NB * NSPL), 256, 0, stream>>>(qkv, vT, bias2, Opart, Lp, Mp);
    comb_kernel<<<NB * SEQ * DM / 4 / 256, 256, 0, stream>>>(Opart, Lp, Mp, attn_o);
    // output projection (fp32 out)
    gemm_kernel<0, 64, 1><<<dim3(DM / 64, NB * SEQ / 128), 256, 0, stream>>>(attn_o, WoT, o_b, d_out,
                                                                             NB * SEQ, DM, DM);
}

// Round 16
// 205.537 us; speedup vs baseline: 1.0457x; 1.0457x over previous
//
#include <hip/hip_runtime.h>
#include <hip/hip_bf16.h>

typedef unsigned short u16;
typedef __attribute__((ext_vector_type(8))) __bf16 bf16x8;
typedef __attribute__((ext_vector_type(4))) float f32x4;
typedef __attribute__((ext_vector_type(16))) float f32x16;

#define SEQ 2048
#define NB 2
#define NH 16
#define HD 64
#define DM 1024
#define LDQKV 3072
#define KF 576   // folded feature K: 512 h1 + 63 feats + 1 (constant term)
#define LOG2E 1.4426950408889634f
#define NSPL 3   // attention KV splits (tiles: 11/11/10)

__device__ __forceinline__ u16 f2bf(float f) {
    unsigned u = __float_as_uint(f);
    unsigned r = u + 0x7FFFu + ((u >> 16) & 1u);
    return (u16)(r >> 16);
}
__device__ __forceinline__ float bf2f(u16 x) {
    return __uint_as_float(((unsigned)x) << 16);
}
__device__ __forceinline__ unsigned cvt_pk_bf16(float a, float b) {
    unsigned r;
    asm("v_cvt_pk_bf16_f32 %0, %1, %2" : "=v"(r) : "v"(a), "v"(b));
    return r;
}
// async global->LDS DMA, 16B per lane; lds dst wave-uniform base + lane*16B
__device__ __forceinline__ void gl_lds16(const u16* g, u16* l) {
    __builtin_amdgcn_global_load_lds((const __attribute__((address_space(1))) unsigned int*)g,
                                     (__attribute__((address_space(3))) unsigned int*)l, 16, 0, 0);
}
// a % b for a,b < 2^24, b >= 1, via exact fp32 division (trunc off-by-1 fixup)
__device__ __forceinline__ unsigned fmod_u24(unsigned a, unsigned b) {
    float q = truncf(__fdividef((float)a, (float)b));
    int r = (int)a - (int)((unsigned)q * b);
    r += (r < 0) ? (int)b : 0;
    r -= (r >= (int)b) ? (int)b : 0;
    return (unsigned)r;
}

// -------- merged weight prep: z=0..3 transpose q(,scale)/k/v/o ; z=4 cast emb2_w -------
__global__ __launch_bounds__(256) void transw5_kernel(const float* __restrict__ q_w,
                                                      const float* __restrict__ k_w,
                                                      const float* __restrict__ v_w,
                                                      const float* __restrict__ o_w,
                                                      const float* __restrict__ emb2_w,
                                                      u16* __restrict__ WqkvT,
                                                      u16* __restrict__ WoT,
                                                      u16* __restrict__ Wc) {
    const int z = blockIdx.z;
    int tx = threadIdx.x, ty = threadIdx.y;
    if (z >= 4) {
        // cast emb2_w (512x1024 fp32 = 524288 floats) -> Wc rows 0..511 bf16, same layout
        int blin = blockIdx.y * 32 + blockIdx.x;     // 0..1023
        if (blin >= 512) return;                     // 512 blocks x 256 thr x 4 floats
        int i = (blin * 256 + ty * 32 + tx) * 4;
        float4 v = *(const float4*)&emb2_w[i];
        uint2 o;
        o.x = cvt_pk_bf16(v.x, v.y);
        o.y = cvt_pk_bf16(v.z, v.w);
        *(uint2*)&Wc[i] = o;
        return;
    }
    __shared__ float tl[32][33];
    const float* src = (z == 0) ? q_w : (z == 1) ? k_w : (z == 2) ? v_w : o_w;
    u16* dst = (z < 3) ? WqkvT + (size_t)z * 1024 * DM : WoT;
    const float scale = (z == 0) ? 0.125f * LOG2E : 1.0f;
    int n = blockIdx.x * 32 + tx;
    int kbase = blockIdx.y * 32;
#pragma unroll
    for (int i = 0; i < 4; ++i)
        tl[ty + i * 8][tx] = src[(size_t)(kbase + ty + i * 8) * DM + n];
    __syncthreads();
    int k = kbase + tx;
#pragma unroll
    for (int i = 0; i < 4; ++i) {
        int n2 = blockIdx.x * 32 + ty + i * 8;
        dst[(size_t)n2 * DM + k] = f2bf(tl[tx][ty + i * 8] * scale);
    }
}

// ---------------- fold feature weights into Wc rows 512..574; r=63 computes cvec ------
__global__ __launch_bounds__(256) void fold_kernel(const float* __restrict__ log_w,
                                                   const float* __restrict__ prime_w,
                                                   const float* __restrict__ div_w,
                                                   const float* __restrict__ bit_w,
                                                   const float* __restrict__ fus_w,
                                                   const float* __restrict__ emb2_b,
                                                   const float* __restrict__ fus_b,
                                                   const float* __restrict__ log_b,
                                                   const float* __restrict__ prime_b,
                                                   const float* __restrict__ div_b,
                                                   const float* __restrict__ bit_b,
                                                   u16* __restrict__ Wc) {
    const int r = blockIdx.y;  // 0..63
    const int n = blockIdx.x * 256 + threadIdx.x;
    if (r == 63) {
        // constant term: cvec = emb2_b + fus_b + biases pushed through fus_w
        float acc = emb2_b[n] + fus_b[n];
#pragma unroll 4
        for (int m = 0; m < 256; ++m) {
            acc += log_b[m]   * fus_w[(size_t)m * DM + n];
            acc += prime_b[m] * fus_w[(size_t)(256 + m) * DM + n];
            acc += div_b[m]   * fus_w[(size_t)(512 + m) * DM + n];
            acc += bit_b[m]   * fus_w[(size_t)(768 + m) * DM + n];
        }
        Wc[(size_t)575 * DM + n] = f2bf(acc);
        return;
    }
    const float* wrow; int chunk;
    if (r == 0)       { wrow = log_w;                 chunk = 0;   }
    else if (r < 11)  { wrow = prime_w + (r - 1) * 256; chunk = 256; }
    else if (r < 31)  { wrow = div_w + (r - 11) * 256;  chunk = 512; }
    else              { wrow = bit_w + (r - 31) * 256;  chunk = 768; }
    float acc = 0.f;
#pragma unroll 8
    for (int m = 0; m < 256; ++m)
        acc += wrow[m] * fus_w[(size_t)(chunk + m) * DM + n];
    Wc[(size_t)(512 + r) * DM + n] = f2bf(acc);
}

// -------- merged prep: blocks [0,8192)=bias2, [8192,12288)=feat, [12288,12300)=qkvb ----
// bias2 layout (R11): float idx = (((b*32+jt)*16 + rr)*2048 + i)*4 + e, rr = 8c+2g+hi
//   value = gcd-bias(i, j=jt*64+rr*4+e) * gcdw * log2e
__global__ __launch_bounds__(256) void prep_kernel(const int* __restrict__ enc,
                                                   const float* __restrict__ gcd_w,
                                                   const float* __restrict__ emb1_w,
                                                   const float* __restrict__ emb1_b,
                                                   const float* __restrict__ q_b,
                                                   const float* __restrict__ k_b,
                                                   const float* __restrict__ v_b,
                                                   float* __restrict__ bias2,
                                                   u16* __restrict__ F,
                                                   float* __restrict__ qkvb) {
    const int bx = blockIdx.x, t = threadIdx.x;
    if (bx < 8192) {
        int vi = bx * 256 + t;
        int i  = vi & 2047;
        int rr = (vi >> 11) & 15;
        int jt = (vi >> 15) & 31;
        int b  = vi >> 20;
        int j0 = jt * 64 + rr * 4;
        unsigned ei = (unsigned)enc[b * SEQ + i];
        float scale = gcd_w[0] * LOG2E;
        int4 ej4 = *(const int4*)&enc[b * SEQ + j0];
        f32x4 o;
#pragma unroll
        for (int e = 0; e < 4; ++e) {
            unsigned ej = (unsigned)((e == 0) ? ej4.x : (e == 1) ? ej4.y : (e == 2) ? ej4.z : ej4.w);
            unsigned r1 = fmod_u24(ei, ej + 1u);
            unsigned r2 = fmod_u24(ej, ei + 1u);
            float gg = (float)min(r1, r2);
            float mx = (float)(max(ei, ej) + 1u);
            o[e] = (i == j0 + e) ? 0.f : __fdividef(gg, mx) * scale;
        }
        *(f32x4*)&bias2[(size_t)vi * 4] = o;
    } else if (bx < 12288) {
        const int tok = bx - 8192;
        int e = enc[tok];
        float ef = (float)e;
        float nrm = ef / 2147483647.0f;
        for (int k = t; k < 512; k += 256)
            F[(size_t)tok * KF + k] = f2bf(fmaxf(nrm * emb1_w[k] + emb1_b[k], 0.f));
        if (t < 64) {
            float v;
            if (t == 0) v = logf(ef + 1.f);
            else if (t < 11) {
                const int pr[10] = {2, 3, 5, 7, 11, 13, 17, 19, 23, 29};
                v = (e % pr[t - 1] == 0) ? 1.f : 0.f;
            } else if (t < 31) {
                int tv = t - 11 + 2;
                v = (float)(e % tv) / (float)tv;
            } else if (t < 63) {
                int sh = t - 31;
                v = (float)((e >> sh) & 1);
            } else v = 1.0f;   // constant-term column: picks up cvec row of Wc
            F[(size_t)tok * KF + 512 + t] = f2bf(v);
        }
    } else {
        int i = (bx - 12288) * 256 + t;  // 0..3071
        const float C1 = 0.125f * LOG2E;
        qkvb[i] = (i < 1024) ? q_b[i] * C1 : (i < 2048 ? k_b[i - 1024] : v_b[i - 2048]);
    }
}

// ---------------- GEMM (m97 structure): C[M x N] = A @ BT^T (+ bias) ----------------
template <int OUT_BF16, int TN, int HB>
__global__ __launch_bounds__(256) void gemm_kernel(const u16* __restrict__ A,
                                                   const u16* __restrict__ BT,
                                                   const float* __restrict__ bias,
                                                   void* __restrict__ Cv,
                                                   int M, int N, int K) {
    constexpr int FN = TN / 32;
    __shared__ u16 As[128 * 32];
    __shared__ u16 Bs[TN * 32];
    const int t = threadIdx.x;
    const int w = t >> 6, l = t & 63, lr = l & 15, lg = l >> 4;
    const int m0 = blockIdx.y * 128, n0 = blockIdx.x * TN;
    const int wm = (w >> 1) * 64, wn = (w & 1) * (TN / 2);
    const int srow = l >> 2, scol = (l & 3) * 8;

    const u16* gA = &A[(size_t)(m0 + w * 32 + srow) * K + scol];
    u16* lA = &As[w * 1024];
    const u16* gB;
    u16* lB;
    if (TN == 128) { gB = &BT[(size_t)(n0 + w * 32 + srow) * K + scol]; lB = &Bs[w * 1024]; }
    else           { gB = &BT[(size_t)(n0 + w * 16 + srow) * K + scol]; lB = &Bs[w * 512];  }

    f32x4 acc[4][FN] = {};
    for (int k0 = 0; k0 < K; k0 += 32) {
        __syncthreads();
        gl_lds16(gA + k0, lA);
        gl_lds16(gA + k0 + (size_t)16 * K, lA + 512);
        if (TN == 128) {
            gl_lds16(gB + k0, lB);
            gl_lds16(gB + k0 + (size_t)16 * K, lB + 512);
        } else {
            gl_lds16(gB + k0, lB);
        }
        __syncthreads();
        bf16x8 a[4], b[FN];
#pragma unroll
        for (int i = 0; i < 4; ++i) a[i] = *(const bf16x8*)&As[(wm + i * 16 + lr) * 32 + lg * 8];
#pragma unroll
        for (int j = 0; j < FN; ++j) b[j] = *(const bf16x8*)&Bs[(wn + j * 16 + lr) * 32 + lg * 8];
#pragma unroll
        for (int mi = 0; mi < 4; ++mi)
#pragma unroll
            for (int ni = 0; ni < FN; ++ni)
                acc[mi][ni] = __builtin_amdgcn_mfma_f32_16x16x32_bf16(a[mi], b[ni], acc[mi][ni], 0, 0, 0);
    }
#pragma unroll
    for (int mi = 0; mi < 4; ++mi)
#pragma unroll
        for (int ni = 0; ni < FN; ++ni)
#pragma unroll
            for (int r = 0; r < 4; ++r) {
                int row = m0 + wm + mi * 16 + lg * 4 + r;
                int col = n0 + wn + ni * 16 + lr;
                float v = acc[mi][ni][r] + (HB ? bias[col] : 0.f);
                if (OUT_BF16)
                    ((u16*)Cv)[(size_t)row * N + col] = f2bf(v);
                else
                    ((float*)Cv)[(size_t)row * N + col] = v;
            }
}

// ---------------- V transpose: vT[b][h][d][s] = v[b][s][h][d] ----------------
__global__ __launch_bounds__(256) void vtrans_kernel(const u16* __restrict__ qkv,
                                                     u16* __restrict__ vT) {
    __shared__ u16 tile[64][72];
    int t = threadIdx.x;
    int s0 = blockIdx.x * 64, h = blockIdx.y, b = blockIdx.z;
    int sr = t >> 2, sc = (t & 3) * 16;
    const int4* g = (const int4*)&qkv[(size_t)(b * SEQ + s0 + sr) * LDQKV + 2048 + h * HD + sc];
    int4 v0 = g[0], v1 = g[1];
    *(int4*)&tile[sr][sc] = v0;
    *(int4*)&tile[sr][sc + 8] = v1;
    __syncthreads();
    int dl = sr, j0 = sc;
    u16 tmp[16];
#pragma unroll
    for (int jj = 0; jj < 16; ++jj) tmp[jj] = tile[j0 + jj][dl];
    u16* out = &vT[(size_t)((b * NH + h) * HD + dl) * SEQ + s0 + j0];
    *(int4*)&out[0] = *(int4*)&tmp[0];
    *(int4*)&out[8] = *(int4*)&tmp[8];
}

// ---------------- fused attention: 32x32x16 MFMA, dbuf KV, KV-split x3 (11/11/10) -----
// Per wave: 32 q rows. S^T = mfma32(K, Q) with bias C-init. P via per-wave LDS.
// C layout (m74/m101): col=lane&31, row=(reg&3)+8*(reg>>2)+4*(lane>>5).
#define KVB 64
#define SWZ(row, cb) ((((int)(row)) << 7) + (((int)(cb)) ^ ((((int)(row)) & 7) << 4)))

__global__ __launch_bounds__(256, 3) void attn_kernel(const u16* __restrict__ qkv,
                                                      const u16* __restrict__ vT,
                                                      const float* __restrict__ bias2,
                                                      u16* __restrict__ Opart,
                                                      float* __restrict__ Lp,
                                                      float* __restrict__ Mp) {
    __shared__ char smem[49152];   // [2][Kt 8KB | Vt 8KB] | Pl 4 x 4KB
    const int t = threadIdx.x, w = t >> 6, l = t & 63;
    const int q5 = l & 31, hi = l >> 5;
    char* PlB = smem + 32768 + (w << 12);
    const int qt = blockIdx.x, h = blockIdx.y;
    const int b = blockIdx.z / NSPL, sp = blockIdx.z % NSPL;
    const int qrow = qt * 128 + w * 32 + q5;
    const int jt0 = sp * 11;                       // first kv tile of this split
    const int NT  = (sp == 2) ? 10 : 11;           // tiles: 11/11/10
    const int j0s = jt0 * KVB;

    // Q B-frags: col=q=q5, k=d=16ks+8hi+j  (Q pre-scaled by 0.125*log2e)
    bf16x8 qf[4];
#pragma unroll
    for (int ks = 0; ks < 4; ++ks)
        qf[ks] = *(const bf16x8*)&qkv[(size_t)(b * SEQ + qrow) * LDQKV + h * HD + ks * 16 + hi * 8];

    // staging addresses
    const int sr = t >> 2, sc = (t & 3) * 16;
    const u16* gK = &qkv[(size_t)(b * SEQ + j0s + sr) * LDQKV + 1024 + h * HD + sc];
    const u16* gV = &vT[(size_t)((b * NH + h) * HD + sr) * SEQ + j0s + sc];
    // bias base: float idx = (((b*32+jt)*16 + rr)*2048 + i)*4 ; rr = 8c+2g+hi
    const float* gBl = &bias2[((((size_t)b * 32 + jt0) * 16 + hi) * 2048 + qrow) * 4];

    // prologue: prefetch tile 0
    int4 kr0 = *(const int4*)&gK[0], kr1 = *(const int4*)&gK[8];
    int4 vr0 = *(const int4*)&gV[0], vr1 = *(const int4*)&gV[8];
    f32x4 br[8];   // [c*4+g]
#pragma unroll
    for (int c = 0; c < 2; ++c)
#pragma unroll
        for (int g = 0; g < 4; ++g)
            br[c * 4 + g] = *(const f32x4*)&gBl[(size_t)(8 * c + 2 * g) << 13];

    float m_s = -1e30f, l_s = 0.f;
    f32x16 acc2[2] = {};

    for (int lt = 0; lt < NT; ++lt) {
        char* KtB = smem + (lt & 1) * 16384;
        char* VtB = KtB + 8192;
        // staged regs -> LDS (swizzled)
        *(int4*)(KtB + SWZ(sr, (t & 3) * 32))      = kr0;
        *(int4*)(KtB + SWZ(sr, (t & 3) * 32 + 16)) = kr1;
        *(int4*)(VtB + SWZ(sr, (t & 3) * 32))      = vr0;
        *(int4*)(VtB + SWZ(sr, (t & 3) * 32 + 16)) = vr1;
        if (lt < NT - 1) {
            kr0 = *(const int4*)&gK[(size_t)(lt + 1) * KVB * LDQKV];
            kr1 = *(const int4*)&gK[(size_t)(lt + 1) * KVB * LDQKV + 8];
            vr0 = *(const int4*)&gV[(lt + 1) * KVB];
            vr1 = *(const int4*)&gV[(lt + 1) * KVB + 8];
        }
        __syncthreads();

        // C-init from bias regs: s2[c][4g+e] = bias(kv=32c+8g+4hi+e, q=q5)
        f32x16 s2[2];
#pragma unroll
        for (int c = 0; c < 2; ++c)
#pragma unroll
            for (int g = 0; g < 4; ++g)
#pragma unroll
                for (int e = 0; e < 4; ++e)
                    s2[c][g * 4 + e] = br[c * 4 + g][e];
        // prefetch next tile's bias
        if (lt < NT - 1) {
            const float* nB = gBl + ((size_t)(lt + 1) << 17);
#pragma unroll
            for (int c = 0; c < 2; ++c)
#pragma unroll
                for (int g = 0; g < 4; ++g)
                    br[c * 4 + g] = *(const f32x4*)&nB[(size_t)(8 * c + 2 * g) << 13];
        }

        // S^T = K @ Q^T : 8 mfma32
        __builtin_amdgcn_s_setprio(1);
#pragma unroll
        for (int ks = 0; ks < 4; ++ks)
#pragma unroll
            for (int c = 0; c < 2; ++c) {
                bf16x8 kf = *(const bf16x8*)(KtB + SWZ(32 * c + q5, ks * 32 + hi * 16));
                s2[c] = __builtin_amdgcn_mfma_f32_32x32x16_bf16(kf, qf[ks], s2[c], 0, 0, 0);
            }
        __builtin_amdgcn_s_setprio(0);

        // softmax (log2 domain): lane holds 32 of 64 kv for q=q5; partner l^32 the rest
        float tm = s2[0][0];
#pragma unroll
        for (int c = 0; c < 2; ++c)
#pragma unroll
            for (int r = 0; r < 16; ++r) tm = fmaxf(tm, s2[c][r]);
        tm = fmaxf(tm, __shfl_xor(tm, 32));

        if (__any(tm > m_s + 8.f)) {
            float mn = fmaxf(m_s, tm);
            float al = __builtin_exp2f(m_s - mn);
            l_s *= al;
            m_s = mn;
#pragma unroll
            for (int dc = 0; dc < 2; ++dc)
#pragma unroll
                for (int r = 0; r < 16; ++r) acc2[dc][r] *= al;
        }

        float ps = 0.f;
#pragma unroll
        for (int c = 0; c < 2; ++c)
#pragma unroll
            for (int r = 0; r < 16; ++r) {
                float p = __builtin_exp2f(s2[c][r] - m_s);
                s2[c][r] = p;
                ps += p;
            }
        ps += __shfl_xor(ps, 32);
        l_s += ps;

        // P -> per-wave LDS: Pl[q][kv], b64 writes at kv = 32c+8g+4hi
#pragma unroll
        for (int c = 0; c < 2; ++c)
#pragma unroll
            for (int g = 0; g < 4; ++g) {
                uint2 u;
                u.x = cvt_pk_bf16(s2[c][4 * g + 0], s2[c][4 * g + 1]);
                u.y = cvt_pk_bf16(s2[c][4 * g + 2], s2[c][4 * g + 3]);
                *(uint2*)(PlB + SWZ(q5, (32 * c + 8 * g + 4 * hi) * 2)) = u;
            }
        asm volatile("s_waitcnt lgkmcnt(0)" ::: "memory");
        __builtin_amdgcn_sched_barrier(0);

        // PV: O^T = V^T @ P^T : 8 mfma32
        __builtin_amdgcn_s_setprio(1);
#pragma unroll
        for (int ks = 0; ks < 4; ++ks) {
            bf16x8 pb = *(const bf16x8*)(PlB + SWZ(q5, ks * 32 + hi * 16));
#pragma unroll
            for (int dc = 0; dc < 2; ++dc) {
                bf16x8 vf = *(const bf16x8*)(VtB + SWZ(32 * dc + q5, ks * 32 + hi * 16));
                acc2[dc] = __builtin_amdgcn_mfma_f32_32x32x16_bf16(vf, pb, acc2[dc], 0, 0, 0);
            }
        }
        __builtin_amdgcn_s_setprio(0);
    }

    // epilogue: unnormalized O~ + (m,l); lane reg r of acc2[dc] -> d = 32dc+8*(r>>2)+4hi+(r&3)
    u16* orow = &Opart[(size_t)((sp * NB + b) * SEQ + qrow) * DM + h * HD];
#pragma unroll
    for (int dc = 0; dc < 2; ++dc)
#pragma unroll
        for (int g = 0; g < 4; ++g) {
            uint2 u;
            u.x = cvt_pk_bf16(acc2[dc][4 * g + 0], acc2[dc][4 * g + 1]);
            u.y = cvt_pk_bf16(acc2[dc][4 * g + 2], acc2[dc][4 * g + 3]);
            *(uint2*)&orow[32 * dc + 8 * g + 4 * hi] = u;
        }
    if (hi == 0) {
        size_t idx = ((size_t)(sp * NB + b) * SEQ + qrow) * NH + h;
        Lp[idx] = l_s;
        Mp[idx] = m_s;
    }
}

// ---------------- combine the three KV-split partials ----------------
__global__ __launch_bounds__(256) void comb_kernel(const u16* __restrict__ Opart,
                                                   const float* __restrict__ Lp,
                                                   const float* __restrict__ Mp,
                                                   u16* __restrict__ attn_o) {
    int tid = blockIdx.x * 256 + threadIdx.x;
    int base = tid * 4;
    int b = base / (SEQ * DM);
    int rem = base - b * SEQ * DM;
    int i = rem / DM;
    int c = rem - i * DM;
    int h = c >> 6;
    size_t ix[3];
    float m[3], lv[3];
#pragma unroll
    for (int s = 0; s < 3; ++s) {
        ix[s] = ((size_t)(s * NB + b) * SEQ + i) * NH + h;
        m[s] = Mp[ix[s]];
        lv[s] = Lp[ix[s]];
    }
    float ms = fmaxf(fmaxf(m[0], m[1]), m[2]);
    float a0 = __builtin_exp2f(m[0] - ms);
    float a1 = __builtin_exp2f(m[1] - ms);
    float a2 = __builtin_exp2f(m[2] - ms);
    float inv = 1.f / (a0 * lv[0] + a1 * lv[1] + a2 * lv[2]);
    a0 *= inv; a1 *= inv; a2 *= inv;
    uint2 o0 = *(const uint2*)&Opart[((size_t)(0 * NB + b) * SEQ + i) * DM + c];
    uint2 o1 = *(const uint2*)&Opart[((size_t)(1 * NB + b) * SEQ + i) * DM + c];
    uint2 o2 = *(const uint2*)&Opart[((size_t)(2 * NB + b) * SEQ + i) * DM + c];
    float v0 = a0 * bf2f(o0.x & 0xFFFF) + a1 * bf2f(o1.x & 0xFFFF) + a2 * bf2f(o2.x & 0xFFFF);
    float v1 = a0 * bf2f(o0.x >> 16)    + a1 * bf2f(o1.x >> 16)    + a2 * bf2f(o2.x >> 16);
    float v2 = a0 * bf2f(o0.y & 0xFFFF) + a1 * bf2f(o1.y & 0xFFFF) + a2 * bf2f(o2.y & 0xFFFF);
    float v3 = a0 * bf2f(o0.y >> 16)    + a1 * bf2f(o1.y >> 16)    + a2 * bf2f(o2.y >> 16);
    uint2 u;
    u.x = cvt_pk_bf16(v0, v1);
    u.y = cvt_pk_bf16(v2, v3);
    *(uint2*)&attn_o[(size_t)(b * SEQ + i) * DM + c] = u;
}

extern "C" void kernel_launch(void* const* d_in, const int* in_sizes, int n_in,
                              void* d_out, int out_size, void* d_ws, size_t ws_size,
                              hipStream_t stream) {
    const float* q_w    = (const float*)d_in[0];
    const float* q_b    = (const float*)d_in[1];
    const float* k_w    = (const float*)d_in[2];
    const float* k_b    = (const float*)d_in[3];
    const float* v_w    = (const float*)d_in[4];
    const float* v_b    = (const float*)d_in[5];
    const float* o_w    = (const float*)d_in[6];
    const float* o_b    = (const float*)d_in[7];
    const float* emb1_w = (const float*)d_in[8];
    const float* emb1_b = (const float*)d_in[9];
    const float* emb2_w = (const float*)d_in[10];
    const float* emb2_b = (const float*)d_in[11];
    const float* log_w  = (const float*)d_in[12];
    const float* log_b  = (const float*)d_in[13];
    const float* prime_w= (const float*)d_in[14];
    const float* prime_b= (const float*)d_in[15];
    const float* div_w  = (const float*)d_in[16];
    const float* div_b  = (const float*)d_in[17];
    const float* bit_w  = (const float*)d_in[18];
    const float* bit_b  = (const float*)d_in[19];
    const float* fus_w  = (const float*)d_in[20];
    const float* fus_b  = (const float*)d_in[21];
    const float* gcd_weight = (const float*)d_in[23];
    const int*   enc    = (const int*)d_in[24];

    char* ws = (char*)d_ws;
    size_t off = 0;
    auto alloc = [&](size_t bytes) {
        char* p = ws + off;
        off += (bytes + 255) & ~size_t(255);
        return p;
    };
    u16*   WqkvT  = (u16*)alloc((size_t)3072 * DM * 2);
    u16*   WoT    = (u16*)alloc((size_t)DM * DM * 2);
    u16*   Wc     = (u16*)alloc((size_t)KF * DM * 2);
    u16*   W2T    = (u16*)alloc((size_t)3072 * KF * 2);
    float* qkvb   = (float*)alloc(3072 * 4);
    u16*   F      = (u16*)alloc((size_t)NB * SEQ * KF * 2);
    u16*   qkv    = (u16*)alloc((size_t)NB * SEQ * LDQKV * 2);
    u16*   vT     = (u16*)alloc((size_t)NB * NH * HD * SEQ * 2);
    float* bias2  = (float*)alloc((size_t)NB * SEQ * SEQ * 4);
    u16*   attn_o = (u16*)alloc((size_t)NB * SEQ * DM * 2);
    u16*   Opart  = (u16*)alloc((size_t)NSPL * NB * SEQ * DM * 2);
    float* Lp     = (float*)alloc((size_t)NSPL * NB * SEQ * NH * 4);
    float* Mp     = (float*)alloc((size_t)NSPL * NB * SEQ * NH * 4);
    (void)ws_size; (void)n_in; (void)in_sizes; (void)out_size;

    // weight prep (q_w pre-scaled so scores come out in log2 domain) + emb2 cast
    transw5_kernel<<<dim3(32, 32, 5), dim3(32, 8), 0, stream>>>(q_w, k_w, v_w, o_w, emb2_w,
                                                                WqkvT, WoT, Wc);
    fold_kernel<<<dim3(4, 64), 256, 0, stream>>>(log_w, prime_w, div_w, bit_w, fus_w,
                                                 emb2_b, fus_b, log_b, prime_b, div_b, bit_b, Wc);
    // bias2 + features + qkv bias in one launch
    prep_kernel<<<12300, 256, 0, stream>>>(enc, gcd_weight, emb1_w, emb1_b, q_b, k_b, v_b,
                                           bias2, F, qkvb);
    // W2T = WqkvT @ Wc^T   (3072 x 576, K=1024) -- hidden GEMM + cvec folded into weights
    gemm_kernel<1, 64, 0><<<dim3(KF / 64, 3072 / 128), 256, 0, stream>>>(WqkvT, Wc, nullptr, W2T,
                                                                         3072, KF, DM);
    // qkv = F @ W2T^T + qkvb   (K=576)
    gemm_kernel<1, 128, 1><<<dim3(3072 / 128, NB * SEQ / 128), 256, 0, stream>>>(F, W2T, qkvb, qkv,
                                                                                 NB * SEQ, 3072, KF);
    vtrans_kernel<<<dim3(SEQ / 64, NH, NB), 256, 0, stream>>>(qkv, vT);
    attn_kernel<<<dim3(SEQ / 128, NH, NB * NSPL), 256, 0, stream>>>(qkv, vT, bias2, Opart, Lp, Mp);
    comb_kernel<<<NB * SEQ * DM / 4 / 256, 256, 0, stream>>>(Opart, Lp, Mp, attn_o);
    // output projection (fp32 out)
    gemm_kernel<0, 64, 1><<<dim3(DM / 64, NB * SEQ / 128), 256, 0, stream>>>(attn_o, WoT, o_b, d_out,
                                                                             NB * SEQ, DM, DM);
}

// Round 17
// 203.284 us; speedup vs baseline: 1.0573x; 1.0111x over previous
//
#include <hip/hip_runtime.h>
#include <hip/hip_bf16.h>

typedef unsigned short u16;
typedef __attribute__((ext_vector_type(8))) __bf16 bf16x8;
typedef __attribute__((ext_vector_type(4))) float f32x4;
typedef __attribute__((ext_vector_type(16))) float f32x16;

#define SEQ 2048
#define NB 2
#define NH 16
#define HD 64
#define DM 1024
#define LDQKV 3072
#define KF 576   // folded feature K: 512 h1 + 63 feats + 1 (constant term)
#define LOG2E 1.4426950408889634f
#define NSPL 3   // attention KV splits (tiles: 11/11/10)

__device__ __forceinline__ u16 f2bf(float f) {
    unsigned u = __float_as_uint(f);
    unsigned r = u + 0x7FFFu + ((u >> 16) & 1u);
    return (u16)(r >> 16);
}
__device__ __forceinline__ float bf2f(u16 x) {
    return __uint_as_float(((unsigned)x) << 16);
}
__device__ __forceinline__ unsigned cvt_pk_bf16(float a, float b) {
    unsigned r;
    asm("v_cvt_pk_bf16_f32 %0, %1, %2" : "=v"(r) : "v"(a), "v"(b));
    return r;
}
// async global->LDS DMA, 16B per lane; lds dst wave-uniform base + lane*16B
__device__ __forceinline__ void gl_lds16(const u16* g, u16* l) {
    __builtin_amdgcn_global_load_lds((const __attribute__((address_space(1))) unsigned int*)g,
                                     (__attribute__((address_space(3))) unsigned int*)l, 16, 0, 0);
}
// a % b for a,b < 2^24, b >= 1, via exact fp32 division (trunc off-by-1 fixup)
__device__ __forceinline__ unsigned fmod_u24(unsigned a, unsigned b) {
    float q = truncf(__fdividef((float)a, (float)b));
    int r = (int)a - (int)((unsigned)q * b);
    r += (r < 0) ? (int)b : 0;
    r -= (r >= (int)b) ? (int)b : 0;
    return (unsigned)r;
}

// -------- merged weight prep: z=0..3 transpose q(,scale)/k/v/o ; z=4 cast emb2_w -------
__global__ __launch_bounds__(256) void transw5_kernel(const float* __restrict__ q_w,
                                                      const float* __restrict__ k_w,
                                                      const float* __restrict__ v_w,
                                                      const float* __restrict__ o_w,
                                                      const float* __restrict__ emb2_w,
                                                      u16* __restrict__ WqkvT,
                                                      u16* __restrict__ WoT,
                                                      u16* __restrict__ Wc) {
    const int z = blockIdx.z;
    int tx = threadIdx.x, ty = threadIdx.y;
    if (z >= 4) {
        // cast emb2_w (512x1024 fp32 = 524288 floats) -> Wc rows 0..511 bf16, same layout
        int blin = blockIdx.y * 32 + blockIdx.x;     // 0..1023
        if (blin >= 512) return;                     // 512 blocks x 256 thr x 4 floats
        int i = (blin * 256 + ty * 32 + tx) * 4;
        float4 v = *(const float4*)&emb2_w[i];
        uint2 o;
        o.x = cvt_pk_bf16(v.x, v.y);
        o.y = cvt_pk_bf16(v.z, v.w);
        *(uint2*)&Wc[i] = o;
        return;
    }
    __shared__ float tl[32][33];
    const float* src = (z == 0) ? q_w : (z == 1) ? k_w : (z == 2) ? v_w : o_w;
    u16* dst = (z < 3) ? WqkvT + (size_t)z * 1024 * DM : WoT;
    const float scale = (z == 0) ? 0.125f * LOG2E : 1.0f;
    int n = blockIdx.x * 32 + tx;
    int kbase = blockIdx.y * 32;
#pragma unroll
    for (int i = 0; i < 4; ++i)
        tl[ty + i * 8][tx] = src[(size_t)(kbase + ty + i * 8) * DM + n];
    __syncthreads();
    int k = kbase + tx;
#pragma unroll
    for (int i = 0; i < 4; ++i) {
        int n2 = blockIdx.x * 32 + ty + i * 8;
        dst[(size_t)n2 * DM + k] = f2bf(tl[tx][ty + i * 8] * scale);
    }
}

// ---------------- fold feature weights into Wc rows 512..574; r=63 computes cvec ------
__global__ __launch_bounds__(256) void fold_kernel(const float* __restrict__ log_w,
                                                   const float* __restrict__ prime_w,
                                                   const float* __restrict__ div_w,
                                                   const float* __restrict__ bit_w,
                                                   const float* __restrict__ fus_w,
                                                   const float* __restrict__ emb2_b,
                                                   const float* __restrict__ fus_b,
                                                   const float* __restrict__ log_b,
                                                   const float* __restrict__ prime_b,
                                                   const float* __restrict__ div_b,
                                                   const float* __restrict__ bit_b,
                                                   u16* __restrict__ Wc) {
    const int r = blockIdx.y;  // 0..63
    const int n = blockIdx.x * 256 + threadIdx.x;
    if (r == 63) {
        // constant term: cvec = emb2_b + fus_b + biases pushed through fus_w
        float acc = emb2_b[n] + fus_b[n];
#pragma unroll 4
        for (int m = 0; m < 256; ++m) {
            acc += log_b[m]   * fus_w[(size_t)m * DM + n];
            acc += prime_b[m] * fus_w[(size_t)(256 + m) * DM + n];
            acc += div_b[m]   * fus_w[(size_t)(512 + m) * DM + n];
            acc += bit_b[m]   * fus_w[(size_t)(768 + m) * DM + n];
        }
        Wc[(size_t)575 * DM + n] = f2bf(acc);
        return;
    }
    const float* wrow; int chunk;
    if (r == 0)       { wrow = log_w;                 chunk = 0;   }
    else if (r < 11)  { wrow = prime_w + (r - 1) * 256; chunk = 256; }
    else if (r < 31)  { wrow = div_w + (r - 11) * 256;  chunk = 512; }
    else              { wrow = bit_w + (r - 31) * 256;  chunk = 768; }
    float acc = 0.f;
#pragma unroll 8
    for (int m = 0; m < 256; ++m)
        acc += wrow[m] * fus_w[(size_t)(chunk + m) * DM + n];
    Wc[(size_t)(512 + r) * DM + n] = f2bf(acc);
}

// -------- merged prep: blocks [0,8192)=bias2, [8192,12288)=feat, [12288,12300)=qkvb ----
// bias2 layout (R11): float idx = (((b*32+jt)*16 + rr)*2048 + i)*4 + e, rr = 8c+2g+hi
//   value = gcd-bias(i, j=jt*64+rr*4+e) * gcdw * log2e
__global__ __launch_bounds__(256) void prep_kernel(const int* __restrict__ enc,
                                                   const float* __restrict__ gcd_w,
                                                   const float* __restrict__ emb1_w,
                                                   const float* __restrict__ emb1_b,
                                                   const float* __restrict__ q_b,
                                                   const float* __restrict__ k_b,
                                                   const float* __restrict__ v_b,
                                                   float* __restrict__ bias2,
                                                   u16* __restrict__ F,
                                                   float* __restrict__ qkvb) {
    const int bx = blockIdx.x, t = threadIdx.x;
    if (bx < 8192) {
        int vi = bx * 256 + t;
        int i  = vi & 2047;
        int rr = (vi >> 11) & 15;
        int jt = (vi >> 15) & 31;
        int b  = vi >> 20;
        int j0 = jt * 64 + rr * 4;
        unsigned ei = (unsigned)enc[b * SEQ + i];
        float scale = gcd_w[0] * LOG2E;
        int4 ej4 = *(const int4*)&enc[b * SEQ + j0];
        f32x4 o;
#pragma unroll
        for (int e = 0; e < 4; ++e) {
            unsigned ej = (unsigned)((e == 0) ? ej4.x : (e == 1) ? ej4.y : (e == 2) ? ej4.z : ej4.w);
            unsigned r1 = fmod_u24(ei, ej + 1u);
            unsigned r2 = fmod_u24(ej, ei + 1u);
            float gg = (float)min(r1, r2);
            float mx = (float)(max(ei, ej) + 1u);
            o[e] = (i == j0 + e) ? 0.f : __fdividef(gg, mx) * scale;
        }
        *(f32x4*)&bias2[(size_t)vi * 4] = o;
    } else if (bx < 12288) {
        const int tok = bx - 8192;
        int e = enc[tok];
        float ef = (float)e;
        float nrm = ef / 2147483647.0f;
        for (int k = t; k < 512; k += 256)
            F[(size_t)tok * KF + k] = f2bf(fmaxf(nrm * emb1_w[k] + emb1_b[k], 0.f));
        if (t < 64) {
            float v;
            if (t == 0) v = logf(ef + 1.f);
            else if (t < 11) {
                const int pr[10] = {2, 3, 5, 7, 11, 13, 17, 19, 23, 29};
                v = (e % pr[t - 1] == 0) ? 1.f : 0.f;
            } else if (t < 31) {
                int tv = t - 11 + 2;
                v = (float)(e % tv) / (float)tv;
            } else if (t < 63) {
                int sh = t - 31;
                v = (float)((e >> sh) & 1);
            } else v = 1.0f;   // constant-term column: picks up cvec row of Wc
            F[(size_t)tok * KF + 512 + t] = f2bf(v);
        }
    } else {
        int i = (bx - 12288) * 256 + t;  // 0..3071
        const float C1 = 0.125f * LOG2E;
        qkvb[i] = (i < 1024) ? q_b[i] * C1 : (i < 2048 ? k_b[i - 1024] : v_b[i - 2048]);
    }
}

// ---------------- GEMM (m97 structure): C[M x N] = A @ BT^T (+ bias) ----------------
template <int OUT_BF16, int TN, int HB>
__global__ __launch_bounds__(256) void gemm_kernel(const u16* __restrict__ A,
                                                   const u16* __restrict__ BT,
                                                   const float* __restrict__ bias,
                                                   void* __restrict__ Cv,
                                                   int M, int N, int K) {
    constexpr int FN = TN / 32;
    __shared__ u16 As[128 * 32];
    __shared__ u16 Bs[TN * 32];
    const int t = threadIdx.x;
    const int w = t >> 6, l = t & 63, lr = l & 15, lg = l >> 4;
    const int m0 = blockIdx.y * 128, n0 = blockIdx.x * TN;
    const int wm = (w >> 1) * 64, wn = (w & 1) * (TN / 2);
    const int srow = l >> 2, scol = (l & 3) * 8;

    const u16* gA = &A[(size_t)(m0 + w * 32 + srow) * K + scol];
    u16* lA = &As[w * 1024];
    const u16* gB;
    u16* lB;
    if (TN == 128) { gB = &BT[(size_t)(n0 + w * 32 + srow) * K + scol]; lB = &Bs[w * 1024]; }
    else           { gB = &BT[(size_t)(n0 + w * 16 + srow) * K + scol]; lB = &Bs[w * 512];  }

    f32x4 acc[4][FN] = {};
    for (int k0 = 0; k0 < K; k0 += 32) {
        __syncthreads();
        gl_lds16(gA + k0, lA);
        gl_lds16(gA + k0 + (size_t)16 * K, lA + 512);
        if (TN == 128) {
            gl_lds16(gB + k0, lB);
            gl_lds16(gB + k0 + (size_t)16 * K, lB + 512);
        } else {
            gl_lds16(gB + k0, lB);
        }
        __syncthreads();
        bf16x8 a[4], b[FN];
#pragma unroll
        for (int i = 0; i < 4; ++i) a[i] = *(const bf16x8*)&As[(wm + i * 16 + lr) * 32 + lg * 8];
#pragma unroll
        for (int j = 0; j < FN; ++j) b[j] = *(const bf16x8*)&Bs[(wn + j * 16 + lr) * 32 + lg * 8];
#pragma unroll
        for (int mi = 0; mi < 4; ++mi)
#pragma unroll
            for (int ni = 0; ni < FN; ++ni)
                acc[mi][ni] = __builtin_amdgcn_mfma_f32_16x16x32_bf16(a[mi], b[ni], acc[mi][ni], 0, 0, 0);
    }
#pragma unroll
    for (int mi = 0; mi < 4; ++mi)
#pragma unroll
        for (int ni = 0; ni < FN; ++ni)
#pragma unroll
            for (int r = 0; r < 4; ++r) {
                int row = m0 + wm + mi * 16 + lg * 4 + r;
                int col = n0 + wn + ni * 16 + lr;
                float v = acc[mi][ni][r] + (HB ? bias[col] : 0.f);
                if (OUT_BF16)
                    ((u16*)Cv)[(size_t)row * N + col] = f2bf(v);
                else
                    ((float*)Cv)[(size_t)row * N + col] = v;
            }
}

// ---------------- V transpose: vT[b][h][d][s] = v[b][s][h][d] ----------------
__global__ __launch_bounds__(256) void vtrans_kernel(const u16* __restrict__ qkv,
                                                     u16* __restrict__ vT) {
    __shared__ u16 tile[64][72];
    int t = threadIdx.x;
    int s0 = blockIdx.x * 64, h = blockIdx.y, b = blockIdx.z;
    int sr = t >> 2, sc = (t & 3) * 16;
    const int4* g = (const int4*)&qkv[(size_t)(b * SEQ + s0 + sr) * LDQKV + 2048 + h * HD + sc];
    int4 v0 = g[0], v1 = g[1];
    *(int4*)&tile[sr][sc] = v0;
    *(int4*)&tile[sr][sc + 8] = v1;
    __syncthreads();
    int dl = sr, j0 = sc;
    u16 tmp[16];
#pragma unroll
    for (int jj = 0; jj < 16; ++jj) tmp[jj] = tile[j0 + jj][dl];
    u16* out = &vT[(size_t)((b * NH + h) * HD + dl) * SEQ + s0 + j0];
    *(int4*)&out[0] = *(int4*)&tmp[0];
    *(int4*)&out[8] = *(int4*)&tmp[8];
}

// ---------------- fused attention: 32x32x16 MFMA, fragment-linear LDS, KV-split x3 ----
// LDS tiles stored fragment-major: subtile (ks,c) = 64 lanes x 16B contiguous.
// Fragment reads are lane-linear (zero bank conflicts, immediate offsets).
// C layout (m74/m101): col=lane&31, row=(reg&3)+8*(reg>>2)+4*(lane>>5).
#define KVB 64

__global__ __launch_bounds__(256, 3) void attn_kernel(const u16* __restrict__ qkv,
                                                      const u16* __restrict__ vT,
                                                      const float* __restrict__ bias2,
                                                      u16* __restrict__ Opart,
                                                      float* __restrict__ Lp,
                                                      float* __restrict__ Mp) {
    __shared__ char smem[49152];   // [2][Kt 8KB | Vt 8KB] | Pl 4 x 4KB
    const int t = threadIdx.x, w = t >> 6, l = t & 63;
    const int q5 = l & 31, hi = l >> 5;
    char* PlB = smem + 32768 + (w << 12);
    const int qt = blockIdx.x, h = blockIdx.y;
    const int b = blockIdx.z / NSPL, sp = blockIdx.z % NSPL;
    const int qrow = qt * 128 + w * 32 + q5;
    const int jt0 = sp * 11;                       // first kv tile of this split
    const int NT  = (sp == 2) ? 10 : 11;           // tiles: 11/11/10
    const int j0s = jt0 * KVB;
    const int lb = l * 16;                         // lane base within a subtile

    // Q B-frags: col=q=q5, k=d=16ks+8hi+j  (Q pre-scaled by 0.125*log2e)
    bf16x8 qf[4];
#pragma unroll
    for (int ks = 0; ks < 4; ++ks)
        qf[ks] = *(const bf16x8*)&qkv[(size_t)(b * SEQ + qrow) * LDQKV + h * HD + ks * 16 + hi * 8];

    // staging addresses: lane t covers chunk (row=sr, colbytes cb=(t&3)*32 and cb+16)
    const int sr = t >> 2;
    const u16* gK = &qkv[(size_t)(b * SEQ + j0s + sr) * LDQKV + 1024 + h * HD + (t & 3) * 16];
    const u16* gV = &vT[(size_t)((b * NH + h) * HD + sr) * SEQ + j0s + (t & 3) * 16];
    // fragment-major dest: subtile (ks=t&3, c=sr>>5), lane slot q5w=sr&31; hi-half at +512
    const int d0 = (((t & 3) * 2 + (sr >> 5)) * 64 + (sr & 31)) * 16;
    // bias base: float idx = (((b*32+jt)*16 + rr)*2048 + i)*4 ; rr = 8c+2g+hi
    const float* gBl = &bias2[((((size_t)b * 32 + jt0) * 16 + hi) * 2048 + qrow) * 4];

    // prologue: prefetch tile 0
    int4 kr0 = *(const int4*)&gK[0], kr1 = *(const int4*)&gK[8];
    int4 vr0 = *(const int4*)&gV[0], vr1 = *(const int4*)&gV[8];
    f32x4 br[8];   // [c*4+g]
#pragma unroll
    for (int c = 0; c < 2; ++c)
#pragma unroll
        for (int g = 0; g < 4; ++g)
            br[c * 4 + g] = *(const f32x4*)&gBl[(size_t)(8 * c + 2 * g) << 13];

    float m_s = -1e30f, l_s = 0.f;
    f32x16 acc2[2] = {};

    for (int lt = 0; lt < NT; ++lt) {
        char* KtB = smem + (lt & 1) * 16384;
        char* VtB = KtB + 8192;
        // staged regs -> LDS (fragment-major scatter; kr0=hi0 chunk, kr1=hi1 chunk)
        *(int4*)(KtB + d0)       = kr0;
        *(int4*)(KtB + d0 + 512) = kr1;
        *(int4*)(VtB + d0)       = vr0;
        *(int4*)(VtB + d0 + 512) = vr1;
        if (lt < NT - 1) {
            kr0 = *(const int4*)&gK[(size_t)(lt + 1) * KVB * LDQKV];
            kr1 = *(const int4*)&gK[(size_t)(lt + 1) * KVB * LDQKV + 8];
            vr0 = *(const int4*)&gV[(lt + 1) * KVB];
            vr1 = *(const int4*)&gV[(lt + 1) * KVB + 8];
        }
        __syncthreads();

        // C-init from bias regs: s2[c][4g+e] = bias(kv=32c+8g+4hi+e, q=q5)
        f32x16 s2[2];
#pragma unroll
        for (int c = 0; c < 2; ++c)
#pragma unroll
            for (int g = 0; g < 4; ++g)
#pragma unroll
                for (int e = 0; e < 4; ++e)
                    s2[c][g * 4 + e] = br[c * 4 + g][e];
        // prefetch next tile's bias
        if (lt < NT - 1) {
            const float* nB = gBl + ((size_t)(lt + 1) << 17);
#pragma unroll
            for (int c = 0; c < 2; ++c)
#pragma unroll
                for (int g = 0; g < 4; ++g)
                    br[c * 4 + g] = *(const f32x4*)&nB[(size_t)(8 * c + 2 * g) << 13];
        }

        // S^T = K @ Q^T : 8 mfma32; K frag (ks,c) at subtile offset (ks*2+c)*1024 + lb
        __builtin_amdgcn_s_setprio(1);
#pragma unroll
        for (int ks = 0; ks < 4; ++ks)
#pragma unroll
            for (int c = 0; c < 2; ++c) {
                bf16x8 kf = *(const bf16x8*)(KtB + (ks * 2 + c) * 1024 + lb);
                s2[c] = __builtin_amdgcn_mfma_f32_32x32x16_bf16(kf, qf[ks], s2[c], 0, 0, 0);
            }
        __builtin_amdgcn_s_setprio(0);

        // softmax (log2 domain): lane holds 32 of 64 kv for q=q5; partner l^32 the rest
        float tm = s2[0][0];
#pragma unroll
        for (int c = 0; c < 2; ++c)
#pragma unroll
            for (int r = 0; r < 16; ++r) tm = fmaxf(tm, s2[c][r]);
        tm = fmaxf(tm, __shfl_xor(tm, 32));

        if (__any(tm > m_s + 8.f)) {
            float mn = fmaxf(m_s, tm);
            float al = __builtin_exp2f(m_s - mn);
            l_s *= al;
            m_s = mn;
#pragma unroll
            for (int dc = 0; dc < 2; ++dc)
#pragma unroll
                for (int r = 0; r < 16; ++r) acc2[dc][r] *= al;
        }

        float ps = 0.f;
#pragma unroll
        for (int c = 0; c < 2; ++c)
#pragma unroll
            for (int r = 0; r < 16; ++r) {
                float p = __builtin_exp2f(s2[c][r] - m_s);
                s2[c][r] = p;
                ps += p;
            }
        ps += __shfl_xor(ps, 32);
        l_s += ps;

        // P -> per-wave LDS (fragment-major): for (c,g) the uint2 covers kv=32c+8g+4hi+e.
        // subtile ks' = 2c+(g>>1); reader half hi' = g&1; j = 4hi+e
        // dest = ks'*1024 + ((g&1)*32 + q5)*16 + hi*8
#pragma unroll
        for (int c = 0; c < 2; ++c)
#pragma unroll
            for (int g = 0; g < 4; ++g) {
                uint2 u;
                u.x = cvt_pk_bf16(s2[c][4 * g + 0], s2[c][4 * g + 1]);
                u.y = cvt_pk_bf16(s2[c][4 * g + 2], s2[c][4 * g + 3]);
                *(uint2*)(PlB + (2 * c + (g >> 1)) * 1024 + ((g & 1) * 32 + q5) * 16 + hi * 8) = u;
            }
        asm volatile("s_waitcnt lgkmcnt(0)" ::: "memory");
        __builtin_amdgcn_sched_barrier(0);

        // PV: O^T = V^T @ P^T : 8 mfma32; P frag ks at ks*1024 + lb, V frag (ks,dc)
        __builtin_amdgcn_s_setprio(1);
#pragma unroll
        for (int ks = 0; ks < 4; ++ks) {
            bf16x8 pb = *(const bf16x8*)(PlB + ks * 1024 + lb);
#pragma unroll
            for (int dc = 0; dc < 2; ++dc) {
                bf16x8 vf = *(const bf16x8*)(VtB + (ks * 2 + dc) * 1024 + lb);
                acc2[dc] = __builtin_amdgcn_mfma_f32_32x32x16_bf16(vf, pb, acc2[dc], 0, 0, 0);
            }
        }
        __builtin_amdgcn_s_setprio(0);
    }

    // epilogue: unnormalized O~ + (m,l); lane reg r of acc2[dc] -> d = 32dc+8*(r>>2)+4hi+(r&3)
    u16* orow = &Opart[(size_t)((sp * NB + b) * SEQ + qrow) * DM + h * HD];
#pragma unroll
    for (int dc = 0; dc < 2; ++dc)
#pragma unroll
        for (int g = 0; g < 4; ++g) {
            uint2 u;
            u.x = cvt_pk_bf16(acc2[dc][4 * g + 0], acc2[dc][4 * g + 1]);
            u.y = cvt_pk_bf16(acc2[dc][4 * g + 2], acc2[dc][4 * g + 3]);
            *(uint2*)&orow[32 * dc + 8 * g + 4 * hi] = u;
        }
    if (hi == 0) {
        size_t idx = ((size_t)(sp * NB + b) * SEQ + qrow) * NH + h;
        Lp[idx] = l_s;
        Mp[idx] = m_s;
    }
}

// ---------------- combine the three KV-split partials ----------------
__global__ __launch_bounds__(256) void comb_kernel(const u16* __restrict__ Opart,
                                                   const float* __restrict__ Lp,
                                                   const float* __restrict__ Mp,
                                                   u16* __restrict__ attn_o) {
    int tid = blockIdx.x * 256 + threadIdx.x;
    int base = tid * 4;
    int b = base / (SEQ * DM);
    int rem = base - b * SEQ * DM;
    int i = rem / DM;
    int c = rem - i * DM;
    int h = c >> 6;
    size_t ix[3];
    float m[3], lv[3];
#pragma unroll
    for (int s = 0; s < 3; ++s) {
        ix[s] = ((size_t)(s * NB + b) * SEQ + i) * NH + h;
        m[s] = Mp[ix[s]];
        lv[s] = Lp[ix[s]];
    }
    float ms = fmaxf(fmaxf(m[0], m[1]), m[2]);
    float a0 = __builtin_exp2f(m[0] - ms);
    float a1 = __builtin_exp2f(m[1] - ms);
    float a2 = __builtin_exp2f(m[2] - ms);
    float inv = 1.f / (a0 * lv[0] + a1 * lv[1] + a2 * lv[2]);
    a0 *= inv; a1 *= inv; a2 *= inv;
    uint2 o0 = *(const uint2*)&Opart[((size_t)(0 * NB + b) * SEQ + i) * DM + c];
    uint2 o1 = *(const uint2*)&Opart[((size_t)(1 * NB + b) * SEQ + i) * DM + c];
    uint2 o2 = *(const uint2*)&Opart[((size_t)(2 * NB + b) * SEQ + i) * DM + c];
    float v0 = a0 * bf2f(o0.x & 0xFFFF) + a1 * bf2f(o1.x & 0xFFFF) + a2 * bf2f(o2.x & 0xFFFF);
    float v1 = a0 * bf2f(o0.x >> 16)    + a1 * bf2f(o1.x >> 16)    + a2 * bf2f(o2.x >> 16);
    float v2 = a0 * bf2f(o0.y & 0xFFFF) + a1 * bf2f(o1.y & 0xFFFF) + a2 * bf2f(o2.y & 0xFFFF);
    float v3 = a0 * bf2f(o0.y >> 16)    + a1 * bf2f(o1.y >> 16)    + a2 * bf2f(o2.y >> 16);
    uint2 u;
    u.x = cvt_pk_bf16(v0, v1);
    u.y = cvt_pk_bf16(v2, v3);
    *(uint2*)&attn_o[(size_t)(b * SEQ + i) * DM + c] = u;
}

extern "C" void kernel_launch(void* const* d_in, const int* in_sizes, int n_in,
                              void* d_out, int out_size, void* d_ws, size_t ws_size,
                              hipStream_t stream) {
    const float* q_w    = (const float*)d_in[0];
    const float* q_b    = (const float*)d_in[1];
    const float* k_w    = (const float*)d_in[2];
    const float* k_b    = (const float*)d_in[3];
    const float* v_w    = (const float*)d_in[4];
    const float* v_b    = (const float*)d_in[5];
    const float* o_w    = (const float*)d_in[6];
    const float* o_b    = (const float*)d_in[7];
    const float* emb1_w = (const float*)d_in[8];
    const float* emb1_b = (const float*)d_in[9];
    const float* emb2_w = (const float*)d_in[10];
    const float* emb2_b = (const float*)d_in[11];
    const float* log_w  = (const float*)d_in[12];
    const float* log_b  = (const float*)d_in[13];
    const float* prime_w= (const float*)d_in[14];
    const float* prime_b= (const float*)d_in[15];
    const float* div_w  = (const float*)d_in[16];
    const float* div_b  = (const float*)d_in[17];
    const float* bit_w  = (const float*)d_in[18];
    const float* bit_b  = (const float*)d_in[19];
    const float* fus_w  = (const float*)d_in[20];
    const float* fus_b  = (const float*)d_in[21];
    const float* gcd_weight = (const float*)d_in[23];
    const int*   enc    = (const int*)d_in[24];

    char* ws = (char*)d_ws;
    size_t off = 0;
    auto alloc = [&](size_t bytes) {
        char* p = ws + off;
        off += (bytes + 255) & ~size_t(255);
        return p;
    };
    u16*   WqkvT  = (u16*)alloc((size_t)3072 * DM * 2);
    u16*   WoT    = (u16*)alloc((size_t)DM * DM * 2);
    u16*   Wc     = (u16*)alloc((size_t)KF * DM * 2);
    u16*   W2T    = (u16*)alloc((size_t)3072 * KF * 2);
    float* qkvb   = (float*)alloc(3072 * 4);
    u16*   F      = (u16*)alloc((size_t)NB * SEQ * KF * 2);
    u16*   qkv    = (u16*)alloc((size_t)NB * SEQ * LDQKV * 2);
    u16*   vT     = (u16*)alloc((size_t)NB * NH * HD * SEQ * 2);
    float* bias2  = (float*)alloc((size_t)NB * SEQ * SEQ * 4);
    u16*   attn_o = (u16*)alloc((size_t)NB * SEQ * DM * 2);
    u16*   Opart  = (u16*)alloc((size_t)NSPL * NB * SEQ * DM * 2);
    float* Lp     = (float*)alloc((size_t)NSPL * NB * SEQ * NH * 4);
    float* Mp     = (float*)alloc((size_t)NSPL * NB * SEQ * NH * 4);
    (void)ws_size; (void)n_in; (void)in_sizes; (void)out_size;

    // weight prep (q_w pre-scaled so scores come out in log2 domain) + emb2 cast
    transw5_kernel<<<dim3(32, 32, 5), dim3(32, 8), 0, stream>>>(q_w, k_w, v_w, o_w, emb2_w,
                                                                WqkvT, WoT, Wc);
    fold_kernel<<<dim3(4, 64), 256, 0, stream>>>(log_w, prime_w, div_w, bit_w, fus_w,
                                                 emb2_b, fus_b, log_b, prime_b, div_b, bit_b, Wc);
    // bias2 + features + qkv bias in one launch
    prep_kernel<<<12300, 256, 0, stream>>>(enc, gcd_weight, emb1_w, emb1_b, q_b, k_b, v_b,
                                           bias2, F, qkvb);
    // W2T = WqkvT @ Wc^T   (3072 x 576, K=1024) -- hidden GEMM + cvec folded into weights
    gemm_kernel<1, 64, 0><<<dim3(KF / 64, 3072 / 128), 256, 0, stream>>>(WqkvT, Wc, nullptr, W2T,
                                                                         3072, KF, DM);
    // qkv = F @ W2T^T + qkvb   (K=576)
    gemm_kernel<1, 128, 1><<<dim3(3072 / 128, NB * SEQ / 128), 256, 0, stream>>>(F, W2T, qkvb, qkv,
                                                                                 NB * SEQ, 3072, KF);
    vtrans_kernel<<<dim3(SEQ / 64, NH, NB), 256, 0, stream>>>(qkv, vT);
    attn_kernel<<<dim3(SEQ / 128, NH, NB * NSPL), 256, 0, stream>>>(qkv, vT, bias2, Opart, Lp, Mp);
    comb_kernel<<<NB * SEQ * DM / 4 / 256, 256, 0, stream>>>(Opart, Lp, Mp, attn_o);
    // output projection (fp32 out)
    gemm_kernel<0, 64, 1><<<dim3(DM / 64, NB * SEQ / 128), 256, 0, stream>>>(attn_o, WoT, o_b, d_out,
                                                                             NB * SEQ, DM, DM);
}